// Round 10
// baseline (12691.661 us; speedup 1.0000x reference)
//
#include <hip/hip_runtime.h>
#include <hip/hip_bf16.h>

#define Bn 4
#define Nn 1024
#define Dn 1024
#define Hn 16
#define DHn 64
#define INNERn 1024
#define SCALEf 0.125f

// ---------------------------------------------------------------------------
// Kernel 1: complex NT GEMM fp32: C[M,E] = A[M,K] * B[E,K]^T
// 64x64 tile, K-tile 16, 256 threads, 4x4 microtile.
// w stored head-major [B,H,N,DH] planar fp32 in ws.
// ---------------------------------------------------------------------------
__global__ __launch_bounds__(256) void gemm_qkv(
    const float* __restrict__ x_re, const float* __restrict__ x_im,
    const float* __restrict__ q_re, const float* __restrict__ q_im,
    float* __restrict__ w_re, float* __restrict__ w_im)
{
    const int K = Dn;
    __shared__ __align__(16) float As_re[16][68], As_im[16][68];
    __shared__ __align__(16) float Bs_re[16][68], Bs_im[16][68];

    int t  = threadIdx.x;
    int tx = t & 15, ty = t >> 4;
    int e0 = blockIdx.x * 64;
    int m0 = blockIdx.y * 64;
    int lrow = t >> 2, lkq = t & 3;

    float cr[4][4] = {{0}}, ci[4][4] = {{0}};

    const float* Arp = x_re + (size_t)(m0 + lrow) * K + lkq * 4;
    const float* Aip = x_im + (size_t)(m0 + lrow) * K + lkq * 4;
    const float* Brp = q_re + (size_t)(e0 + lrow) * K + lkq * 4;
    const float* Bip = q_im + (size_t)(e0 + lrow) * K + lkq * 4;

    for (int k0 = 0; k0 < K; k0 += 16) {
        float4 ar = *(const float4*)(Arp + k0);
        float4 ai = *(const float4*)(Aip + k0);
        float4 br = *(const float4*)(Brp + k0);
        float4 bi = *(const float4*)(Bip + k0);
        __syncthreads();
        As_re[lkq*4+0][lrow] = ar.x; As_re[lkq*4+1][lrow] = ar.y;
        As_re[lkq*4+2][lrow] = ar.z; As_re[lkq*4+3][lrow] = ar.w;
        As_im[lkq*4+0][lrow] = ai.x; As_im[lkq*4+1][lrow] = ai.y;
        As_im[lkq*4+2][lrow] = ai.z; As_im[lkq*4+3][lrow] = ai.w;
        Bs_re[lkq*4+0][lrow] = br.x; Bs_re[lkq*4+1][lrow] = br.y;
        Bs_re[lkq*4+2][lrow] = br.z; Bs_re[lkq*4+3][lrow] = br.w;
        Bs_im[lkq*4+0][lrow] = bi.x; Bs_im[lkq*4+1][lrow] = bi.y;
        Bs_im[lkq*4+2][lrow] = bi.z; Bs_im[lkq*4+3][lrow] = bi.w;
        __syncthreads();
#pragma unroll
        for (int kk = 0; kk < 16; ++kk) {
            float4 a4r = *(const float4*)&As_re[kk][ty*4];
            float4 a4i = *(const float4*)&As_im[kk][ty*4];
            float4 b4r = *(const float4*)&Bs_re[kk][tx*4];
            float4 b4i = *(const float4*)&Bs_im[kk][tx*4];
            float arr[4] = {a4r.x, a4r.y, a4r.z, a4r.w};
            float aii[4] = {a4i.x, a4i.y, a4i.z, a4i.w};
            float brr[4] = {b4r.x, b4r.y, b4r.z, b4r.w};
            float bii[4] = {b4i.x, b4i.y, b4i.z, b4i.w};
#pragma unroll
            for (int i = 0; i < 4; ++i)
#pragma unroll
                for (int j = 0; j < 4; ++j) {
                    cr[i][j] += arr[i]*brr[j] - aii[i]*bii[j];
                    ci[i][j] += arr[i]*bii[j] + aii[i]*brr[j];
                }
        }
    }
#pragma unroll
    for (int i = 0; i < 4; ++i)
#pragma unroll
        for (int j = 0; j < 4; ++j) {
            int m = m0 + ty*4 + i;
            int e = e0 + tx*4 + j;
            int b = m >> 10, n = m & 1023;
            int h = e >> 6,  dh = e & 63;
            size_t idx = (size_t)(b*Hn + h) * (Nn*DHn) + (size_t)n*DHn + dh;
            w_re[idx] = cr[i][j];
            w_im[idx] = ci[i][j];
        }
}

// ---------------------------------------------------------------------------
// Kernel 2: magnitude-softmax attention. One block per (b,h,n). fp32.
// ---------------------------------------------------------------------------
__global__ __launch_bounds__(256) void attn_kernel(
    const float* __restrict__ w_re, const float* __restrict__ w_im,
    float* __restrict__ o_re, float* __restrict__ o_im)
{
    int n  = blockIdx.x;
    int bh = blockIdx.y;
    const float* wr = w_re + (size_t)bh * (Nn*DHn);
    const float* wi = w_im + (size_t)bh * (Nn*DHn);

    __shared__ __align__(16) float q_re[64], q_im[64];
    __shared__ float sc_re[1024], sc_im[1024], mg[1024];
    __shared__ float red[256];

    int t = threadIdx.x;
    if (t < 64) {
        q_re[t] = wr[(size_t)n*64 + t];
        q_im[t] = wi[(size_t)n*64 + t];
    }
    __syncthreads();

    float lmax = -1e30f;
    for (int mm = t; mm < Nn; mm += 256) {
        const float4* rr = (const float4*)(wr + (size_t)mm*64);
        const float4* ri = (const float4*)(wi + (size_t)mm*64);
        float sr = 0.f, si = 0.f;
#pragma unroll
        for (int kq = 0; kq < 16; ++kq) {
            float4 mr = rr[kq], mi = ri[kq];
            float4 qr = *(const float4*)&q_re[kq*4];
            float4 qi = *(const float4*)&q_im[kq*4];
            sr += qr.x*mr.x + qi.x*mi.x;  si += qi.x*mr.x - qr.x*mi.x;
            sr += qr.y*mr.y + qi.y*mi.y;  si += qi.y*mr.y - qr.y*mi.y;
            sr += qr.z*mr.z + qi.z*mi.z;  si += qi.z*mr.z - qr.z*mi.z;
            sr += qr.w*mr.w + qi.w*mi.w;  si += qi.w*mr.w - qr.w*mi.w;
        }
        sr *= SCALEf; si *= SCALEf;
        float mag = sqrtf(sr*sr + si*si);
        sc_re[mm] = sr; sc_im[mm] = si; mg[mm] = mag;
        lmax = fmaxf(lmax, mag);
    }

    red[t] = lmax; __syncthreads();
    for (int s = 128; s >= 1; s >>= 1) {
        if (t < s) red[t] = fmaxf(red[t], red[t + s]);
        __syncthreads();
    }
    float Mx = red[0];
    __syncthreads();

    float lsum = 0.f;
    for (int mm = t; mm < Nn; mm += 256) {
        float mag = mg[mm];
        float a = __expf(mag - Mx);
        lsum += a;
        float cr, ci2;
        if (mag > 0.f) {
            float s = a / mag;
            cr = sc_re[mm] * s;
            ci2 = sc_im[mm] * s;
        } else {
            cr = a; ci2 = 0.f;   // unit = 1 when mag == 0
        }
        sc_re[mm] = cr; sc_im[mm] = ci2;
    }
    red[t] = lsum; __syncthreads();
    for (int s = 128; s >= 1; s >>= 1) {
        if (t < s) red[t] += red[t + s];
        __syncthreads();
    }
    float invt = 1.f / red[0];

    int dh = t & 63, g = t >> 6;
    float ar = 0.f, ai = 0.f;
    for (int mm = g*256; mm < g*256 + 256; ++mm) {
        float cr = sc_re[mm], ci2 = sc_im[mm];
        float w0r = wr[(size_t)mm*64 + dh];
        float w0i = wi[(size_t)mm*64 + dh];
        ar += cr*w0r - ci2*w0i;
        ai += cr*w0i + ci2*w0r;
    }
    __syncthreads();
    sc_re[t] = ar; sc_im[t] = ai;
    __syncthreads();
    if (t < 64) {
        float orr = (sc_re[t] + sc_re[t+64] + sc_re[t+128] + sc_re[t+192]) * invt;
        float oii = (sc_im[t] + sc_im[t+64] + sc_im[t+128] + sc_im[t+192]) * invt;
        int b = bh >> 4, h = bh & 15;
        size_t idx = ((size_t)b*Nn + n) * INNERn + h*DHn + t;
        o_re[idx] = orr;
        o_im[idx] = oii;
    }
}

// ---------------------------------------------------------------------------
// Kernel 3: output projection + bias -> REAL PART ONLY, fp32.
// R9 crash (32MB write) proved d_out is 16 MB; R8 probe proved float32 read.
// => out_size = 4M float32 = [B,N,D] = real(reference output)
//    (dataset flattened complex64 via .astype(np.float32) = real part).
// re(C[m,d]) = sum_e (a_re*w_re - a_im*w_im) + bout_re[d].
// ---------------------------------------------------------------------------
__global__ __launch_bounds__(256) void gemm_out(
    const float* __restrict__ a_re, const float* __restrict__ a_im,
    const float* __restrict__ o_wre, const float* __restrict__ o_wim,
    const float* __restrict__ b_re,
    float* __restrict__ out)
{
    const int K = INNERn;
    __shared__ __align__(16) float As_re[16][68], As_im[16][68];
    __shared__ __align__(16) float Bs_re[16][68], Bs_im[16][68];

    int t  = threadIdx.x;
    int tx = t & 15, ty = t >> 4;
    int d0 = blockIdx.x * 64;
    int m0 = blockIdx.y * 64;
    int lrow = t >> 2, lkq = t & 3;

    float cr[4][4] = {{0}};

    const float* Arp = a_re + (size_t)(m0 + lrow) * K + lkq * 4;
    const float* Aip = a_im + (size_t)(m0 + lrow) * K + lkq * 4;
    const float* Brp = o_wre + (size_t)(d0 + lrow) * K + lkq * 4;
    const float* Bip = o_wim + (size_t)(d0 + lrow) * K + lkq * 4;

    for (int k0 = 0; k0 < K; k0 += 16) {
        float4 ar = *(const float4*)(Arp + k0);
        float4 ai = *(const float4*)(Aip + k0);
        float4 br = *(const float4*)(Brp + k0);
        float4 bi = *(const float4*)(Bip + k0);
        __syncthreads();
        As_re[lkq*4+0][lrow] = ar.x; As_re[lkq*4+1][lrow] = ar.y;
        As_re[lkq*4+2][lrow] = ar.z; As_re[lkq*4+3][lrow] = ar.w;
        As_im[lkq*4+0][lrow] = ai.x; As_im[lkq*4+1][lrow] = ai.y;
        As_im[lkq*4+2][lrow] = ai.z; As_im[lkq*4+3][lrow] = ai.w;
        Bs_re[lkq*4+0][lrow] = br.x; Bs_re[lkq*4+1][lrow] = br.y;
        Bs_re[lkq*4+2][lrow] = br.z; Bs_re[lkq*4+3][lrow] = br.w;
        Bs_im[lkq*4+0][lrow] = bi.x; Bs_im[lkq*4+1][lrow] = bi.y;
        Bs_im[lkq*4+2][lrow] = bi.z; Bs_im[lkq*4+3][lrow] = bi.w;
        __syncthreads();
#pragma unroll
        for (int kk = 0; kk < 16; ++kk) {
            float4 a4r = *(const float4*)&As_re[kk][ty*4];
            float4 a4i = *(const float4*)&As_im[kk][ty*4];
            float4 b4r = *(const float4*)&Bs_re[kk][tx*4];
            float4 b4i = *(const float4*)&Bs_im[kk][tx*4];
            float arr[4] = {a4r.x, a4r.y, a4r.z, a4r.w};
            float aii[4] = {a4i.x, a4i.y, a4i.z, a4i.w};
            float brr[4] = {b4r.x, b4r.y, b4r.z, b4r.w};
            float bii[4] = {b4i.x, b4i.y, b4i.z, b4i.w};
#pragma unroll
            for (int i = 0; i < 4; ++i)
#pragma unroll
                for (int j = 0; j < 4; ++j) {
                    cr[i][j] += arr[i]*brr[j] - aii[i]*bii[j];   // real part only
                }
        }
    }
#pragma unroll
    for (int i = 0; i < 4; ++i)
#pragma unroll
        for (int j = 0; j < 4; ++j) {
            int m = m0 + ty*4 + i;
            int d = d0 + tx*4 + j;
            out[(size_t)m * Dn + d] = cr[i][j] + b_re[d];
        }
}

// ---------------------------------------------------------------------------
extern "C" void kernel_launch(void* const* d_in, const int* in_sizes, int n_in,
                              void* d_out, int out_size, void* d_ws, size_t ws_size,
                              hipStream_t stream) {
    const float* x_re   = (const float*)d_in[0];
    const float* x_im   = (const float*)d_in[1];
    const float* wq_re  = (const float*)d_in[2];
    const float* wq_im  = (const float*)d_in[3];
    const float* wo_re  = (const float*)d_in[4];
    const float* wo_im  = (const float*)d_in[5];
    const float* bo_re  = (const float*)d_in[6];

    const size_t SEG = (size_t)Bn * Nn * INNERn;   // 4M floats
    float* w_re = (float*)d_ws;
    float* w_im = w_re + SEG;
    float* a_re = w_im + SEG;
    float* a_im = a_re + SEG;

    {
        dim3 grid(INNERn / 64, (Bn * Nn) / 64);
        gemm_qkv<<<grid, 256, 0, stream>>>(x_re, x_im, wq_re, wq_im, w_re, w_im);
    }
    {
        dim3 grid(Nn, Bn * Hn);
        attn_kernel<<<grid, 256, 0, stream>>>(w_re, w_im, a_re, a_im);
    }
    {
        dim3 grid(Dn / 64, (Bn * Nn) / 64);
        gemm_out<<<grid, 256, 0, stream>>>(a_re, a_im, wo_re, wo_im, bo_re,
                                           (float*)d_out);
    }
}

// Round 11
// 3050.701 us; speedup vs baseline: 4.1602x; 4.1602x over previous
//
#include <hip/hip_runtime.h>
#include <hip/hip_bf16.h>

#define Bn 4
#define Nn 1024
#define Dn 1024
#define Hn 16
#define DHn 64
#define INNERn 1024
#define SCALEf 0.125f
#define QT 64
#define KT 32

// ---------------------------------------------------------------------------
// Kernel 1: complex NT GEMM fp32: C[M,E] = A[M,K] * B[E,K]^T
// w stored head-major [B,H,N,DH] planar fp32 in ws.  (unchanged from R10)
// ---------------------------------------------------------------------------
__global__ __launch_bounds__(256) void gemm_qkv(
    const float* __restrict__ x_re, const float* __restrict__ x_im,
    const float* __restrict__ q_re, const float* __restrict__ q_im,
    float* __restrict__ w_re, float* __restrict__ w_im)
{
    const int K = Dn;
    __shared__ __align__(16) float As_re[16][68], As_im[16][68];
    __shared__ __align__(16) float Bs_re[16][68], Bs_im[16][68];

    int t  = threadIdx.x;
    int tx = t & 15, ty = t >> 4;
    int e0 = blockIdx.x * 64;
    int m0 = blockIdx.y * 64;
    int lrow = t >> 2, lkq = t & 3;

    float cr[4][4] = {{0}}, ci[4][4] = {{0}};

    const float* Arp = x_re + (size_t)(m0 + lrow) * K + lkq * 4;
    const float* Aip = x_im + (size_t)(m0 + lrow) * K + lkq * 4;
    const float* Brp = q_re + (size_t)(e0 + lrow) * K + lkq * 4;
    const float* Bip = q_im + (size_t)(e0 + lrow) * K + lkq * 4;

    for (int k0 = 0; k0 < K; k0 += 16) {
        float4 ar = *(const float4*)(Arp + k0);
        float4 ai = *(const float4*)(Aip + k0);
        float4 br = *(const float4*)(Brp + k0);
        float4 bi = *(const float4*)(Bip + k0);
        __syncthreads();
        As_re[lkq*4+0][lrow] = ar.x; As_re[lkq*4+1][lrow] = ar.y;
        As_re[lkq*4+2][lrow] = ar.z; As_re[lkq*4+3][lrow] = ar.w;
        As_im[lkq*4+0][lrow] = ai.x; As_im[lkq*4+1][lrow] = ai.y;
        As_im[lkq*4+2][lrow] = ai.z; As_im[lkq*4+3][lrow] = ai.w;
        Bs_re[lkq*4+0][lrow] = br.x; Bs_re[lkq*4+1][lrow] = br.y;
        Bs_re[lkq*4+2][lrow] = br.z; Bs_re[lkq*4+3][lrow] = br.w;
        Bs_im[lkq*4+0][lrow] = bi.x; Bs_im[lkq*4+1][lrow] = bi.y;
        Bs_im[lkq*4+2][lrow] = bi.z; Bs_im[lkq*4+3][lrow] = bi.w;
        __syncthreads();
#pragma unroll
        for (int kk = 0; kk < 16; ++kk) {
            float4 a4r = *(const float4*)&As_re[kk][ty*4];
            float4 a4i = *(const float4*)&As_im[kk][ty*4];
            float4 b4r = *(const float4*)&Bs_re[kk][tx*4];
            float4 b4i = *(const float4*)&Bs_im[kk][tx*4];
            float arr[4] = {a4r.x, a4r.y, a4r.z, a4r.w};
            float aii[4] = {a4i.x, a4i.y, a4i.z, a4i.w};
            float brr[4] = {b4r.x, b4r.y, b4r.z, b4r.w};
            float bii[4] = {b4i.x, b4i.y, b4i.z, b4i.w};
#pragma unroll
            for (int i = 0; i < 4; ++i)
#pragma unroll
                for (int j = 0; j < 4; ++j) {
                    cr[i][j] += arr[i]*brr[j] - aii[i]*bii[j];
                    ci[i][j] += arr[i]*bii[j] + aii[i]*brr[j];
                }
        }
    }
#pragma unroll
    for (int i = 0; i < 4; ++i)
#pragma unroll
        for (int j = 0; j < 4; ++j) {
            int m = m0 + ty*4 + i;
            int e = e0 + tx*4 + j;
            int b = m >> 10, n = m & 1023;
            int h = e >> 6,  dh = e & 63;
            size_t idx = (size_t)(b*Hn + h) * (Nn*DHn) + (size_t)n*DHn + dh;
            w_re[idx] = cr[i][j];
            w_im[idx] = ci[i][j];
        }
}

// ---------------------------------------------------------------------------
// Kernel 2: FLASH-STYLE magnitude-softmax attention.
// One block per (b,h, 64-row Q-tile). K-tiles of 32 rows staged in LDS.
// Online softmax: running m, l, alpha per Q-row; O in registers.
// Coef tile stored TRANSPOSED [m][r] so PV reads are float4 over r.
// ---------------------------------------------------------------------------
__global__ __launch_bounds__(256) void attn_flash(
    const float* __restrict__ w_re, const float* __restrict__ w_im,
    float* __restrict__ o_re, float* __restrict__ o_im)
{
    __shared__ __align__(16) float Qr[QT][68], Qi[QT][68];   // 34.8 KB
    __shared__ __align__(16) float Kr[KT][68], Ki[KT][68];   // 17.4 KB
    __shared__ __align__(16) float Ctr[KT][68], Cti[KT][68]; // 17.4 KB (coef^T)
    __shared__ float Mg[QT][4], Sm[QT][4];                   // 2 KB
    __shared__ float rowm[QT], rowl[QT], alph[QT];           // 0.75 KB

    int t  = threadIdx.x;
    int qt = blockIdx.x;           // 0..15
    int bh = blockIdx.y;           // 0..63
    const float* wr = w_re + (size_t)bh * (Nn*DHn);
    const float* wi = w_im + (size_t)bh * (Nn*DHn);
    int n0 = qt * QT;

    // load Q tile: row = t>>2, 4 threads/row, 4 float4 chunks each
    {
        int r = t >> 2;
        int cbase = (t & 3) * 16;
#pragma unroll
        for (int i = 0; i < 4; ++i) {
            int c = cbase + i*4;
            float4 vr = *(const float4*)(wr + (size_t)(n0+r)*DHn + c);
            float4 vi = *(const float4*)(wi + (size_t)(n0+r)*DHn + c);
            *(float4*)&Qr[r][c] = vr;
            *(float4*)&Qi[r][c] = vi;
        }
    }
    if (t < QT) { rowm[t] = -1e30f; rowl[t] = 0.f; }

    // O accumulators: wave wv owns rows [wv*16, wv*16+16), lane owns dh
    int dh = t & 63;
    int wv = t >> 6;
    int r0 = wv * 16;
    float Or[16], Oi[16];
#pragma unroll
    for (int i = 0; i < 16; ++i) { Or[i] = 0.f; Oi[i] = 0.f; }

    int srow = t >> 2;   // score row (0..63)
    int m4   = t & 3;    // score col subset: m = m4 + 4j

    for (int kt = 0; kt < Nn/KT; ++kt) {
        __syncthreads();   // protect Kr/Ct/alph from previous iteration's PV
        // load K tile: row = t>>3, 8 threads/row, 2 float4 chunks each
        {
            int r = t >> 3;
            int cbase = (t & 7) * 8;
#pragma unroll
            for (int i = 0; i < 2; ++i) {
                int c = cbase + i*4;
                float4 vr = *(const float4*)(wr + (size_t)(kt*KT + r)*DHn + c);
                float4 vi = *(const float4*)(wi + (size_t)(kt*KT + r)*DHn + c);
                *(float4*)&Kr[r][c] = vr;
                *(float4*)&Ki[r][c] = vi;
            }
        }
        __syncthreads();   // K tile ready

        // ---- scores: 8 per thread (row srow, cols m4+4j) ----
        float sre[8], sim[8];
#pragma unroll
        for (int j = 0; j < 8; ++j) { sre[j] = 0.f; sim[j] = 0.f; }
#pragma unroll
        for (int d4 = 0; d4 < 16; ++d4) {
            float4 q4r = *(const float4*)&Qr[srow][d4*4];
            float4 q4i = *(const float4*)&Qi[srow][d4*4];
#pragma unroll
            for (int j = 0; j < 8; ++j) {
                int m = m4 + 4*j;
                float4 k4r = *(const float4*)&Kr[m][d4*4];
                float4 k4i = *(const float4*)&Ki[m][d4*4];
                sre[j] += q4r.x*k4r.x + q4i.x*k4i.x
                        + q4r.y*k4r.y + q4i.y*k4i.y
                        + q4r.z*k4r.z + q4i.z*k4i.z
                        + q4r.w*k4r.w + q4i.w*k4i.w;
                sim[j] += q4i.x*k4r.x - q4r.x*k4i.x
                        + q4i.y*k4r.y - q4r.y*k4i.y
                        + q4i.z*k4r.z - q4r.z*k4i.z
                        + q4i.w*k4r.w - q4r.w*k4i.w;
            }
        }
        float mag[8];
        float pmax = -1e30f;
#pragma unroll
        for (int j = 0; j < 8; ++j) {
            sre[j] *= SCALEf; sim[j] *= SCALEf;
            mag[j] = sqrtf(sre[j]*sre[j] + sim[j]*sim[j]);
            pmax = fmaxf(pmax, mag[j]);
        }
        Mg[srow][m4] = pmax;
        __syncthreads();   // Mg ready
        if (t < QT) {
            float mnew = fmaxf(fmaxf(Mg[t][0], Mg[t][1]), fmaxf(Mg[t][2], Mg[t][3]));
            mnew = fmaxf(rowm[t], mnew);
            alph[t] = __expf(rowm[t] - mnew);
            rowm[t] = mnew;
        }
        __syncthreads();   // rowm/alph ready

        // ---- coef = exp(mag-m)*s/|s| (or exp when |s|==0), transposed store ----
        {
            float mn = rowm[srow];
            float psum = 0.f;
#pragma unroll
            for (int j = 0; j < 8; ++j) {
                int m = m4 + 4*j;
                float e = __expf(mag[j] - mn);
                psum += e;
                float cr, ci;
                if (mag[j] > 0.f) {
                    float s = e / mag[j];
                    cr = sre[j] * s; ci = sim[j] * s;
                } else { cr = e; ci = 0.f; }
                Ctr[m][srow] = cr;
                Cti[m][srow] = ci;
            }
            Sm[srow][m4] = psum;
        }
        __syncthreads();   // coef + Sm ready
        if (t < QT) {
            rowl[t] = rowl[t]*alph[t] + (Sm[t][0]+Sm[t][1]+Sm[t][2]+Sm[t][3]);
        }

        // ---- PV: O[r][dh] = O*alpha + sum_m coef[r][m] * w[m][dh] ----
#pragma unroll
        for (int i = 0; i < 16; ++i) {
            float a = alph[r0+i];
            Or[i] *= a; Oi[i] *= a;
        }
        for (int m = 0; m < KT; ++m) {
            float kr = Kr[m][dh], ki = Ki[m][dh];
#pragma unroll
            for (int i4 = 0; i4 < 4; ++i4) {
                float4 c4r = *(const float4*)&Ctr[m][r0 + i4*4];
                float4 c4i = *(const float4*)&Cti[m][r0 + i4*4];
                Or[i4*4+0] += c4r.x*kr - c4i.x*ki;
                Oi[i4*4+0] += c4r.x*ki + c4i.x*kr;
                Or[i4*4+1] += c4r.y*kr - c4i.y*ki;
                Oi[i4*4+1] += c4r.y*ki + c4i.y*kr;
                Or[i4*4+2] += c4r.z*kr - c4i.z*ki;
                Oi[i4*4+2] += c4r.z*ki + c4i.z*kr;
                Or[i4*4+3] += c4r.w*kr - c4i.w*ki;
                Oi[i4*4+3] += c4r.w*ki + c4i.w*kr;
            }
        }
    }
    __syncthreads();   // rowl final values visible to all

    // normalize + write: attn-out [B,N,INNER], INNER index = h*64+dh
    int b = bh >> 4, h = bh & 15;
#pragma unroll
    for (int i = 0; i < 16; ++i) {
        float inv = 1.f / rowl[r0+i];
        int n = n0 + r0 + i;
        size_t idx = ((size_t)b*Nn + n) * INNERn + h*DHn + dh;
        o_re[idx] = Or[i]*inv;
        o_im[idx] = Oi[i]*inv;
    }
}

// ---------------------------------------------------------------------------
// Kernel 3: output projection + bias -> real part only, fp32 (verified R10).
// ---------------------------------------------------------------------------
__global__ __launch_bounds__(256) void gemm_out(
    const float* __restrict__ a_re, const float* __restrict__ a_im,
    const float* __restrict__ o_wre, const float* __restrict__ o_wim,
    const float* __restrict__ b_re,
    float* __restrict__ out)
{
    const int K = INNERn;
    __shared__ __align__(16) float As_re[16][68], As_im[16][68];
    __shared__ __align__(16) float Bs_re[16][68], Bs_im[16][68];

    int t  = threadIdx.x;
    int tx = t & 15, ty = t >> 4;
    int d0 = blockIdx.x * 64;
    int m0 = blockIdx.y * 64;
    int lrow = t >> 2, lkq = t & 3;

    float cr[4][4] = {{0}};

    const float* Arp = a_re + (size_t)(m0 + lrow) * K + lkq * 4;
    const float* Aip = a_im + (size_t)(m0 + lrow) * K + lkq * 4;
    const float* Brp = o_wre + (size_t)(d0 + lrow) * K + lkq * 4;
    const float* Bip = o_wim + (size_t)(d0 + lrow) * K + lkq * 4;

    for (int k0 = 0; k0 < K; k0 += 16) {
        float4 ar = *(const float4*)(Arp + k0);
        float4 ai = *(const float4*)(Aip + k0);
        float4 br = *(const float4*)(Brp + k0);
        float4 bi = *(const float4*)(Bip + k0);
        __syncthreads();
        As_re[lkq*4+0][lrow] = ar.x; As_re[lkq*4+1][lrow] = ar.y;
        As_re[lkq*4+2][lrow] = ar.z; As_re[lkq*4+3][lrow] = ar.w;
        As_im[lkq*4+0][lrow] = ai.x; As_im[lkq*4+1][lrow] = ai.y;
        As_im[lkq*4+2][lrow] = ai.z; As_im[lkq*4+3][lrow] = ai.w;
        Bs_re[lkq*4+0][lrow] = br.x; Bs_re[lkq*4+1][lrow] = br.y;
        Bs_re[lkq*4+2][lrow] = br.z; Bs_re[lkq*4+3][lrow] = br.w;
        Bs_im[lkq*4+0][lrow] = bi.x; Bs_im[lkq*4+1][lrow] = bi.y;
        Bs_im[lkq*4+2][lrow] = bi.z; Bs_im[lkq*4+3][lrow] = bi.w;
        __syncthreads();
#pragma unroll
        for (int kk = 0; kk < 16; ++kk) {
            float4 a4r = *(const float4*)&As_re[kk][ty*4];
            float4 a4i = *(const float4*)&As_im[kk][ty*4];
            float4 b4r = *(const float4*)&Bs_re[kk][tx*4];
            float4 b4i = *(const float4*)&Bs_im[kk][tx*4];
            float arr[4] = {a4r.x, a4r.y, a4r.z, a4r.w};
            float aii[4] = {a4i.x, a4i.y, a4i.z, a4i.w};
            float brr[4] = {b4r.x, b4r.y, b4r.z, b4r.w};
            float bii[4] = {b4i.x, b4i.y, b4i.z, b4i.w};
#pragma unroll
            for (int i = 0; i < 4; ++i)
#pragma unroll
                for (int j = 0; j < 4; ++j) {
                    cr[i][j] += arr[i]*brr[j] - aii[i]*bii[j];   // real part only
                }
        }
    }
#pragma unroll
    for (int i = 0; i < 4; ++i)
#pragma unroll
        for (int j = 0; j < 4; ++j) {
            int m = m0 + ty*4 + i;
            int d = d0 + tx*4 + j;
            out[(size_t)m * Dn + d] = cr[i][j] + b_re[d];
        }
}

// ---------------------------------------------------------------------------
extern "C" void kernel_launch(void* const* d_in, const int* in_sizes, int n_in,
                              void* d_out, int out_size, void* d_ws, size_t ws_size,
                              hipStream_t stream) {
    const float* x_re   = (const float*)d_in[0];
    const float* x_im   = (const float*)d_in[1];
    const float* wq_re  = (const float*)d_in[2];
    const float* wq_im  = (const float*)d_in[3];
    const float* wo_re  = (const float*)d_in[4];
    const float* wo_im  = (const float*)d_in[5];
    const float* bo_re  = (const float*)d_in[6];

    const size_t SEG = (size_t)Bn * Nn * INNERn;   // 4M floats
    float* w_re = (float*)d_ws;
    float* w_im = w_re + SEG;
    float* a_re = w_im + SEG;
    float* a_im = a_re + SEG;

    {
        dim3 grid(INNERn / 64, (Bn * Nn) / 64);
        gemm_qkv<<<grid, 256, 0, stream>>>(x_re, x_im, wq_re, wq_im, w_re, w_im);
    }
    {
        dim3 grid(Nn / QT, Bn * Hn);
        attn_flash<<<grid, 256, 0, stream>>>(w_re, w_im, a_re, a_im);
    }
    {
        dim3 grid(Dn / 64, (Bn * Nn) / 64);
        gemm_out<<<grid, 256, 0, stream>>>(a_re, a_im, wo_re, wo_im, bo_re,
                                           (float*)d_out);
    }
}

// Round 12
// 1349.370 us; speedup vs baseline: 9.4056x; 2.2608x over previous
//
#include <hip/hip_runtime.h>
#include <hip/hip_bf16.h>

#define Bn 4
#define Nn 1024
#define Dn 1024
#define Hn 16
#define DHn 64
#define INNERn 1024
#define SCALEf 0.125f

typedef unsigned short u16;
using bf16x8 = __attribute__((ext_vector_type(8))) short;
using f32x4  = __attribute__((ext_vector_type(4))) float;

__device__ __forceinline__ u16 f2bf(float f) {
    __hip_bfloat16 h = __float2bfloat16(f);
    return *(u16*)&h;
}

// ---------------------------------------------------------------------------
// Kernel 1: complex NT GEMM fp32 (unchanged, verified R10).
// ---------------------------------------------------------------------------
__global__ __launch_bounds__(256) void gemm_qkv(
    const float* __restrict__ x_re, const float* __restrict__ x_im,
    const float* __restrict__ q_re, const float* __restrict__ q_im,
    float* __restrict__ w_re, float* __restrict__ w_im)
{
    const int K = Dn;
    __shared__ __align__(16) float As_re[16][68], As_im[16][68];
    __shared__ __align__(16) float Bs_re[16][68], Bs_im[16][68];

    int t  = threadIdx.x;
    int tx = t & 15, ty = t >> 4;
    int e0 = blockIdx.x * 64;
    int m0 = blockIdx.y * 64;
    int lrow = t >> 2, lkq = t & 3;

    float cr[4][4] = {{0}}, ci[4][4] = {{0}};

    const float* Arp = x_re + (size_t)(m0 + lrow) * K + lkq * 4;
    const float* Aip = x_im + (size_t)(m0 + lrow) * K + lkq * 4;
    const float* Brp = q_re + (size_t)(e0 + lrow) * K + lkq * 4;
    const float* Bip = q_im + (size_t)(e0 + lrow) * K + lkq * 4;

    for (int k0 = 0; k0 < K; k0 += 16) {
        float4 ar = *(const float4*)(Arp + k0);
        float4 ai = *(const float4*)(Aip + k0);
        float4 br = *(const float4*)(Brp + k0);
        float4 bi = *(const float4*)(Bip + k0);
        __syncthreads();
        As_re[lkq*4+0][lrow] = ar.x; As_re[lkq*4+1][lrow] = ar.y;
        As_re[lkq*4+2][lrow] = ar.z; As_re[lkq*4+3][lrow] = ar.w;
        As_im[lkq*4+0][lrow] = ai.x; As_im[lkq*4+1][lrow] = ai.y;
        As_im[lkq*4+2][lrow] = ai.z; As_im[lkq*4+3][lrow] = ai.w;
        Bs_re[lkq*4+0][lrow] = br.x; Bs_re[lkq*4+1][lrow] = br.y;
        Bs_re[lkq*4+2][lrow] = br.z; Bs_re[lkq*4+3][lrow] = br.w;
        Bs_im[lkq*4+0][lrow] = bi.x; Bs_im[lkq*4+1][lrow] = bi.y;
        Bs_im[lkq*4+2][lrow] = bi.z; Bs_im[lkq*4+3][lrow] = bi.w;
        __syncthreads();
#pragma unroll
        for (int kk = 0; kk < 16; ++kk) {
            float4 a4r = *(const float4*)&As_re[kk][ty*4];
            float4 a4i = *(const float4*)&As_im[kk][ty*4];
            float4 b4r = *(const float4*)&Bs_re[kk][tx*4];
            float4 b4i = *(const float4*)&Bs_im[kk][tx*4];
            float arr[4] = {a4r.x, a4r.y, a4r.z, a4r.w};
            float aii[4] = {a4i.x, a4i.y, a4i.z, a4i.w};
            float brr[4] = {b4r.x, b4r.y, b4r.z, b4r.w};
            float bii[4] = {b4i.x, b4i.y, b4i.z, b4i.w};
#pragma unroll
            for (int i = 0; i < 4; ++i)
#pragma unroll
                for (int j = 0; j < 4; ++j) {
                    cr[i][j] += arr[i]*brr[j] - aii[i]*bii[j];
                    ci[i][j] += arr[i]*bii[j] + aii[i]*brr[j];
                }
        }
    }
#pragma unroll
    for (int i = 0; i < 4; ++i)
#pragma unroll
        for (int j = 0; j < 4; ++j) {
            int m = m0 + ty*4 + i;
            int e = e0 + tx*4 + j;
            int b = m >> 10, n = m & 1023;
            int h = e >> 6,  dh = e & 63;
            size_t idx = (size_t)(b*Hn + h) * (Nn*DHn) + (size_t)n*DHn + dh;
            w_re[idx] = cr[i][j];
            w_im[idx] = ci[i][j];
        }
}

// ---------------------------------------------------------------------------
// Kernel 2: MFMA flash attention (bf16 16x16x32).
// Block = (b,h, 64-row Q tile), 256 thr = 4 waves; wave owns 16 Q-rows.
// K-tiles of 32 rows. Complex S via 4 real MFMAs (Qrn = -Qr staged).
// P: C-layout -> LDS bf16 -> A-layout. PV B-op from transposed K staging
// (Ktr/Kti/Ktin = -Kti). Online magnitude-softmax in fp32.
// ---------------------------------------------------------------------------
__global__ __launch_bounds__(256) void attn_mfma(
    const float* __restrict__ w_re, const float* __restrict__ w_im,
    float* __restrict__ o_re, float* __restrict__ o_im)
{
    // LDS (62.4 KB total -> 2 blocks/CU)
    __shared__ __align__(16) u16 Qr[64][72], Qi[64][72], Qrn[64][72]; // 27.6 KB
    __shared__ __align__(16) u16 Kr[32][72], Ki[32][72];              //  9.2 KB
    __shared__ __align__(16) u16 Ktr[64][40], Kti[64][40], Ktin[64][40]; // 15.4 KB
    __shared__ __align__(16) u16 Pr[64][40], Pi[64][40];              // 10.2 KB

    int t    = threadIdx.x;
    int lane = t & 63;
    int wv   = t >> 6;          // 0..3
    int lq   = lane & 15;       // col / row-frag index
    int qd   = lane >> 4;       // quad 0..3
    int r0   = wv * 16;         // wave's Q-row base

    int n0 = blockIdx.x * 64;
    int bh = blockIdx.y;
    int b  = bh >> 4, h = bh & 15;
    const float* wr = w_re + (size_t)bh * (Nn*DHn);
    const float* wi = w_im + (size_t)bh * (Nn*DHn);

    // ---- stage Q tile (once): row t>>2, dh-chunk (t&3)*16 ----
    {
        int r = t >> 2;
        int c0 = (t & 3) * 16;
        const float* pr = wr + (size_t)(n0 + r) * DHn + c0;
        const float* pi = wi + (size_t)(n0 + r) * DHn + c0;
#pragma unroll
        for (int j = 0; j < 16; ++j) {
            float vr = pr[j], vi = pi[j];
            Qr [r][c0+j] = f2bf(vr);
            Qi [r][c0+j] = f2bf(vi);
            Qrn[r][c0+j] = f2bf(-vr);
        }
    }
    __syncthreads();

    // ---- hoist Q fragments (A-op: row = r0+lq, k = chunk*32 + qd*8+j) ----
    bf16x8 qfr[2], qfi[2], qfn[2];
#pragma unroll
    for (int c = 0; c < 2; ++c) {
        qfr[c] = *(const bf16x8*)&Qr [r0 + lq][c*32 + qd*8];
        qfi[c] = *(const bf16x8*)&Qi [r0 + lq][c*32 + qd*8];
        qfn[c] = *(const bf16x8*)&Qrn[r0 + lq][c*32 + qd*8];
    }

    // softmax state (replicated over the 16 lanes of each quad-group)
    float rm[4], rl[4];
#pragma unroll
    for (int p = 0; p < 4; ++p) { rm[p] = -1e30f; rl[p] = 0.f; }
    // O accumulators: 4 dh-tiles x complex, rows r0 + qd*4 + p
    f32x4 Ore[4], Oim[4];
#pragma unroll
    for (int d = 0; d < 4; ++d) { Ore[d] = (f32x4)0.f; Oim[d] = (f32x4)0.f; }

    for (int kt = 0; kt < Nn/32; ++kt) {
        __syncthreads();   // prev PV / P reads done before restaging
        // ---- stage K tile: row m = t>>3 (0..31), dh-chunk (t&7)*8 ----
        {
            int m  = t >> 3;
            int dc = (t & 7) * 8;
            const float* pr = wr + (size_t)(kt*32 + m) * DHn + dc;
            const float* pi = wi + (size_t)(kt*32 + m) * DHn + dc;
#pragma unroll
            for (int j = 0; j < 8; ++j) {
                float vr = pr[j], vi = pi[j];
                int dh = dc + j;
                Kr [m][dh] = f2bf(vr);
                Ki [m][dh] = f2bf(vi);
                Ktr [dh][m] = f2bf(vr);
                Kti [dh][m] = f2bf(vi);
                Ktin[dh][m] = f2bf(-vi);
            }
        }
        __syncthreads();   // staging visible

        // ---- scores: 2 col-tiles of 16, rows r0..r0+15 ----
        float sre[2][4], sim[2][4], mag[2][4];
#pragma unroll
        for (int ct = 0; ct < 2; ++ct) {
            bf16x8 bkr[2], bki[2];
#pragma unroll
            for (int c = 0; c < 2; ++c) {
                bkr[c] = *(const bf16x8*)&Kr[ct*16 + lq][c*32 + qd*8];
                bki[c] = *(const bf16x8*)&Ki[ct*16 + lq][c*32 + qd*8];
            }
            f32x4 are = (f32x4)0.f, aim = (f32x4)0.f;
            are = __builtin_amdgcn_mfma_f32_16x16x32_bf16(qfr[0], bkr[0], are, 0,0,0);
            are = __builtin_amdgcn_mfma_f32_16x16x32_bf16(qfi[0], bki[0], are, 0,0,0);
            are = __builtin_amdgcn_mfma_f32_16x16x32_bf16(qfr[1], bkr[1], are, 0,0,0);
            are = __builtin_amdgcn_mfma_f32_16x16x32_bf16(qfi[1], bki[1], are, 0,0,0);
            aim = __builtin_amdgcn_mfma_f32_16x16x32_bf16(qfi[0], bkr[0], aim, 0,0,0);
            aim = __builtin_amdgcn_mfma_f32_16x16x32_bf16(qfn[0], bki[0], aim, 0,0,0);
            aim = __builtin_amdgcn_mfma_f32_16x16x32_bf16(qfi[1], bkr[1], aim, 0,0,0);
            aim = __builtin_amdgcn_mfma_f32_16x16x32_bf16(qfn[1], bki[1], aim, 0,0,0);
#pragma unroll
            for (int p = 0; p < 4; ++p) {
                float r = are[p] * SCALEf;
                float i = aim[p] * SCALEf;
                sre[ct][p] = r; sim[ct][p] = i;
                mag[ct][p] = sqrtf(r*r + i*i);
            }
        }

        // ---- online softmax: row = r0 + qd*4 + p ----
        float alpha[4];
#pragma unroll
        for (int p = 0; p < 4; ++p) {
            float pm = fmaxf(mag[0][p], mag[1][p]);
            pm = fmaxf(pm, __shfl_xor(pm, 1));
            pm = fmaxf(pm, __shfl_xor(pm, 2));
            pm = fmaxf(pm, __shfl_xor(pm, 4));
            pm = fmaxf(pm, __shfl_xor(pm, 8));
            float mnew = fmaxf(rm[p], pm);
            alpha[p] = __expf(rm[p] - mnew);
            rm[p] = mnew;
        }
        // coef -> P (bf16), row-sums
#pragma unroll
        for (int p = 0; p < 4; ++p) {
            float s = 0.f;
            int q = r0 + qd*4 + p;
#pragma unroll
            for (int ct = 0; ct < 2; ++ct) {
                float mg = mag[ct][p];
                float e = __expf(mg - rm[p]);
                s += e;
                float cr, ci;
                if (mg > 0.f) {
                    float f = e / mg;
                    cr = sre[ct][p] * f; ci = sim[ct][p] * f;
                } else { cr = e; ci = 0.f; }
                Pr[q][ct*16 + lq] = f2bf(cr);
                Pi[q][ct*16 + lq] = f2bf(ci);
            }
            s += __shfl_xor(s, 1);
            s += __shfl_xor(s, 2);
            s += __shfl_xor(s, 4);
            s += __shfl_xor(s, 8);
            rl[p] = rl[p]*alpha[p] + s;
        }

        // ---- rescale O by alpha ----
#pragma unroll
        for (int d = 0; d < 4; ++d)
#pragma unroll
            for (int p = 0; p < 4; ++p) {
                Ore[d][p] *= alpha[p];
                Oim[d][p] *= alpha[p];
            }
        __syncthreads();   // P writes visible

        // ---- PV: O[r0..r0+15][dh] += P * Wtile ----
        bf16x8 par = *(const bf16x8*)&Pr[r0 + lq][qd*8];
        bf16x8 pai = *(const bf16x8*)&Pi[r0 + lq][qd*8];
#pragma unroll
        for (int d = 0; d < 4; ++d) {
            bf16x8 fr  = *(const bf16x8*)&Ktr [d*16 + lq][qd*8];
            bf16x8 fi  = *(const bf16x8*)&Kti [d*16 + lq][qd*8];
            bf16x8 fin = *(const bf16x8*)&Ktin[d*16 + lq][qd*8];
            Ore[d] = __builtin_amdgcn_mfma_f32_16x16x32_bf16(par, fr,  Ore[d], 0,0,0);
            Ore[d] = __builtin_amdgcn_mfma_f32_16x16x32_bf16(pai, fin, Ore[d], 0,0,0);
            Oim[d] = __builtin_amdgcn_mfma_f32_16x16x32_bf16(par, fi,  Oim[d], 0,0,0);
            Oim[d] = __builtin_amdgcn_mfma_f32_16x16x32_bf16(pai, fr,  Oim[d], 0,0,0);
        }
    }

    // ---- epilogue: normalize, write attn-out [B,N,INNER] ----
#pragma unroll
    for (int p = 0; p < 4; ++p) {
        float inv = 1.f / rl[p];
        int n = n0 + r0 + qd*4 + p;
#pragma unroll
        for (int d = 0; d < 4; ++d) {
            int dh = d*16 + lq;
            size_t idx = ((size_t)b*Nn + n) * INNERn + h*DHn + dh;
            o_re[idx] = Ore[d][p] * inv;
            o_im[idx] = Oim[d][p] * inv;
        }
    }
}

// ---------------------------------------------------------------------------
// Kernel 3: output projection + bias -> real part only, fp32 (verified R10).
// ---------------------------------------------------------------------------
__global__ __launch_bounds__(256) void gemm_out(
    const float* __restrict__ a_re, const float* __restrict__ a_im,
    const float* __restrict__ o_wre, const float* __restrict__ o_wim,
    const float* __restrict__ b_re,
    float* __restrict__ out)
{
    const int K = INNERn;
    __shared__ __align__(16) float As_re[16][68], As_im[16][68];
    __shared__ __align__(16) float Bs_re[16][68], Bs_im[16][68];

    int t  = threadIdx.x;
    int tx = t & 15, ty = t >> 4;
    int d0 = blockIdx.x * 64;
    int m0 = blockIdx.y * 64;
    int lrow = t >> 2, lkq = t & 3;

    float cr[4][4] = {{0}};

    const float* Arp = a_re + (size_t)(m0 + lrow) * K + lkq * 4;
    const float* Aip = a_im + (size_t)(m0 + lrow) * K + lkq * 4;
    const float* Brp = o_wre + (size_t)(d0 + lrow) * K + lkq * 4;
    const float* Bip = o_wim + (size_t)(d0 + lrow) * K + lkq * 4;

    for (int k0 = 0; k0 < K; k0 += 16) {
        float4 ar = *(const float4*)(Arp + k0);
        float4 ai = *(const float4*)(Aip + k0);
        float4 br = *(const float4*)(Brp + k0);
        float4 bi = *(const float4*)(Bip + k0);
        __syncthreads();
        As_re[lkq*4+0][lrow] = ar.x; As_re[lkq*4+1][lrow] = ar.y;
        As_re[lkq*4+2][lrow] = ar.z; As_re[lkq*4+3][lrow] = ar.w;
        As_im[lkq*4+0][lrow] = ai.x; As_im[lkq*4+1][lrow] = ai.y;
        As_im[lkq*4+2][lrow] = ai.z; As_im[lkq*4+3][lrow] = ai.w;
        Bs_re[lkq*4+0][lrow] = br.x; Bs_re[lkq*4+1][lrow] = br.y;
        Bs_re[lkq*4+2][lrow] = br.z; Bs_re[lkq*4+3][lrow] = br.w;
        Bs_im[lkq*4+0][lrow] = bi.x; Bs_im[lkq*4+1][lrow] = bi.y;
        Bs_im[lkq*4+2][lrow] = bi.z; Bs_im[lkq*4+3][lrow] = bi.w;
        __syncthreads();
#pragma unroll
        for (int kk = 0; kk < 16; ++kk) {
            float4 a4r = *(const float4*)&As_re[kk][ty*4];
            float4 a4i = *(const float4*)&As_im[kk][ty*4];
            float4 b4r = *(const float4*)&Bs_re[kk][tx*4];
            float4 b4i = *(const float4*)&Bs_im[kk][tx*4];
            float arr[4] = {a4r.x, a4r.y, a4r.z, a4r.w};
            float aii[4] = {a4i.x, a4i.y, a4i.z, a4i.w};
            float brr[4] = {b4r.x, b4r.y, b4r.z, b4r.w};
            float bii[4] = {b4i.x, b4i.y, b4i.z, b4i.w};
#pragma unroll
            for (int i = 0; i < 4; ++i)
#pragma unroll
                for (int j = 0; j < 4; ++j) {
                    cr[i][j] += arr[i]*brr[j] - aii[i]*bii[j];   // real part only
                }
        }
    }
#pragma unroll
    for (int i = 0; i < 4; ++i)
#pragma unroll
        for (int j = 0; j < 4; ++j) {
            int m = m0 + ty*4 + i;
            int d = d0 + tx*4 + j;
            out[(size_t)m * Dn + d] = cr[i][j] + b_re[d];
        }
}

// ---------------------------------------------------------------------------
extern "C" void kernel_launch(void* const* d_in, const int* in_sizes, int n_in,
                              void* d_out, int out_size, void* d_ws, size_t ws_size,
                              hipStream_t stream) {
    const float* x_re   = (const float*)d_in[0];
    const float* x_im   = (const float*)d_in[1];
    const float* wq_re  = (const float*)d_in[2];
    const float* wq_im  = (const float*)d_in[3];
    const float* wo_re  = (const float*)d_in[4];
    const float* wo_im  = (const float*)d_in[5];
    const float* bo_re  = (const float*)d_in[6];

    const size_t SEG = (size_t)Bn * Nn * INNERn;   // 4M floats
    float* w_re = (float*)d_ws;
    float* w_im = w_re + SEG;
    float* a_re = w_im + SEG;
    float* a_im = a_re + SEG;

    {
        dim3 grid(INNERn / 64, (Bn * Nn) / 64);
        gemm_qkv<<<grid, 256, 0, stream>>>(x_re, x_im, wq_re, wq_im, w_re, w_im);
    }
    {
        dim3 grid(Nn / 64, Bn * Hn);
        attn_mfma<<<grid, 256, 0, stream>>>(w_re, w_im, a_re, a_im);
    }
    {
        dim3 grid(Dn / 64, (Bn * Nn) / 64);
        gemm_out<<<grid, 256, 0, stream>>>(a_re, a_im, wo_re, wo_im, bo_re,
                                           (float*)d_out);
    }
}